// Round 11
// baseline (168.259 us; speedup 1.0000x reference)
//
#include <hip/hip_runtime.h>
#include <hip/hip_bf16.h>

#define B_    4
#define N_    20000
#define M_    20000
#define K_    16
#define CIN   64
#define CMID  16
#define COUT  67            // CIN + 3 additional channels
#define PPB   4             // one point per wave, 4 waves per block
#define NXCD  8
#define LSTR  17            // padded transpose stride (f32)

typedef float float4_ __attribute__((ext_vector_type(4)));
typedef short short8_ __attribute__((ext_vector_type(8)));

static __device__ __forceinline__ unsigned pk2(float lo, float hi) {
    unsigned short l = __builtin_bit_cast(unsigned short, __float2bfloat16(lo));
    unsigned short h = __builtin_bit_cast(unsigned short, __float2bfloat16(hi));
    return (unsigned)l | ((unsigned)h << 16);
}

static __device__ __forceinline__ short8_ mk8(unsigned p0, unsigned p1,
                                              unsigned p2, unsigned p3) {
    union { unsigned u[4]; short8_ s; } x;
    x.u[0] = p0; x.u[1] = p1; x.u[2] = p2; x.u[3] = p3;
    return x.s;
}

__global__ __launch_bounds__(256, 6) void pconv_kernel(
    const float* __restrict__ in_feats,   // [B, N, 64]
    const int*   __restrict__ inds,       // [B, M, 16]
    const float* __restrict__ wn,         // [B, M, 16, 16]
    const float* __restrict__ addl,       // [B, M, 16, 3]
    float*       __restrict__ out)        // [B, M, 1072]
{
    // wave-private buffers; lds_buf = feats[16][64] phase 1, out-transpose phase 2
    __shared__ float lds_buf[PPB][1152];          // 4.5 KB/wave (union)
    __shared__ float lds_wn [PPB][K_ * CMID];     // 1 KB/wave
    __shared__ float lds_ad [PPB][48];            // 192 B/wave

    const int tid  = threadIdx.x;
    const int lane = tid & 63;
    const int wav  = tid >> 6;
    const int n16  = lane & 15;
    const int hi   = lane >> 4;

    // bijective XCD swizzle (20000 % 8 == 0)
    const int qx  = gridDim.x / NXCD;
    const int swz = (blockIdx.x % NXCD) * qx + blockIdx.x / NXCD;

    const int bp = __builtin_amdgcn_readfirstlane(swz * PPB + wav);
    const int b  = bp / M_;

    const int*   pinds = inds + (long)bp * K_;
    const float* pwn   = wn   + (long)bp * (K_ * CMID);
    const float* padd  = addl + (long)bp * (K_ * 3);
    const float* bfeat = in_feats + (long)b * N_ * CIN;

    // ---- streaming loads issued first ----
    float4_ wstage = ((const float4_*)pwn)[lane];            // 1 KB coalesced
    float   astage = (lane < 48) ? padd[lane] : 0.f;         // 192 B

    // ---- 16 neighbor indices -> SGPRs (SMEM overlaps the loads above) ----
    int idxs[K_];
    #pragma unroll
    for (int k = 0; k < K_; ++k) idxs[k] = pinds[k];

    // ---- 4 dwordx4 gathers: group g -> row idx[4g+hi], cols 4*n16..+3 ----
    float4_ gat[4];
    #pragma unroll
    for (int g = 0; g < 4; ++g) {
        int row = idxs[g * 4 + 0];
        row = (hi == 1) ? idxs[g * 4 + 1] : row;
        row = (hi == 2) ? idxs[g * 4 + 2] : row;
        row = (hi == 3) ? idxs[g * 4 + 3] : row;
        gat[g] = *(const float4_*)(bfeat + (long)row * CIN + n16 * 4);
    }

    // ---- stage to wave-private LDS (no barriers anywhere) ----
    float* lf = &lds_buf[wav][0];
    #pragma unroll
    for (int g = 0; g < 4; ++g)
        *(float4_*)(lf + (g * 4 + hi) * CIN + n16 * 4) = gat[g];   // feats[k][c]
    *(float4_*)(&lds_wn[wav][lane * 4]) = wstage;                  // wn[k][w]
    if (lane < 48) lds_ad[wav][lane] = astage;                     // addl[k][t]

    // Fragment slot map: element j at lane(hi) covers kk=(hi&1)*8+j; hi>=2
    // lanes read the SAME LDS address as hi-2 (broadcast, conflict-free) and
    // B zeroes those slots -> MFMA sums exactly k=0..15 (validated R9/R10).
    const int kkb = (hi & 1) * 8;

    // ---- B fragment ----
    float bwv[8];
    #pragma unroll
    for (int j = 0; j < 8; ++j)
        bwv[j] = lds_wn[wav][(kkb + j) * CMID + n16];
    const bool realk = hi < 2;
    short8_ bfrag = mk8(realk ? pk2(bwv[0], bwv[1]) : 0u,
                        realk ? pk2(bwv[2], bwv[3]) : 0u,
                        realk ? pk2(bwv[4], bwv[5]) : 0u,
                        realk ? pk2(bwv[6], bwv[7]) : 0u);

    // ---- tail-A fragment (addl channels), rows >=3 unused ----
    const int mcl = (n16 < 3) ? n16 : 2;
    float atv[8];
    #pragma unroll
    for (int j = 0; j < 8; ++j)
        atv[j] = lds_ad[wav][(kkb + j) * 3 + mcl];
    short8_ tfrag = mk8(pk2(atv[0], atv[1]), pk2(atv[2], atv[3]),
                        pk2(atv[4], atv[5]), pk2(atv[6], atv[7]));

    // ---- main A fragments + MFMAs ----
    float4_ zero = (float4_)0.f;
    float4_ acc[4];
    #pragma unroll
    for (int t = 0; t < 4; ++t) {
        float av[8];
        #pragma unroll
        for (int j = 0; j < 8; ++j)
            av[j] = lf[(kkb + j) * CIN + t * 16 + n16];    // 2-addr/bank, free
        short8_ afrag = mk8(pk2(av[0], av[1]), pk2(av[2], av[3]),
                            pk2(av[4], av[5]), pk2(av[6], av[7]));
        acc[t] = __builtin_amdgcn_mfma_f32_16x16x32_bf16(afrag, bfrag, zero, 0, 0, 0);
    }
    float4_ acc4 = __builtin_amdgcn_mfma_f32_16x16x32_bf16(tfrag, bfrag, zero, 0, 0, 0);

    // ---- transpose D via padded LDS (reuse lf; same-wave LDS is in-order) ----
    // D layout (HW-verified): col=n16, row=hi*4+reg
    #pragma unroll
    for (int t = 0; t < 4; ++t) {
        #pragma unroll
        for (int r = 0; r < 4; ++r)
            lf[(t * 16 + hi * 4 + r) * LSTR + n16] = acc[t][r];
    }
    if (hi == 0) {
        #pragma unroll
        for (int r = 0; r < 3; ++r)
            lf[(CIN + r) * LSTR + n16] = acc4[r];          // channels 64..66
    }

    // ---- readback + contiguous stores: 4 x 1KB + 192B ----
    float* pout = out + (long)bp * (COUT * CMID);
    const int q  = lane >> 2;
    const int r2 = lane & 3;
    #pragma unroll
    for (int pp = 0; pp < 4; ++pp) {
        const float* src = lf + (pp * 16 + q) * LSTR + 4 * r2;
        float4_ v = { src[0], src[1], src[2], src[3] };
        *(float4_*)(pout + pp * 256 + lane * 4) = v;
    }
    if (lane < 12) {
        const float* src = lf + (CIN + q) * LSTR + 4 * r2;
        float4_ v = { src[0], src[1], src[2], src[3] };
        *(float4_*)(pout + 1024 + lane * 4) = v;
    }
}

extern "C" void kernel_launch(void* const* d_in, const int* in_sizes, int n_in,
                              void* d_out, int out_size, void* d_ws, size_t ws_size,
                              hipStream_t stream) {
    const float* in_feats = (const float*)d_in[0];
    const int*   ninds    = (const int*)d_in[1];
    const float* wnp      = (const float*)d_in[2];
    const float* addl     = (const float*)d_in[3];
    float*       outp     = (float*)d_out;

    const int total_points = B_ * M_;            // 80000
    dim3 grid(total_points / PPB);               // 20000 blocks, 1 point/wave
    dim3 block(256);
    pconv_kernel<<<grid, block, 0, stream>>>(in_feats, ninds, wnp, addl, outp);
}

// Round 12
// 134.883 us; speedup vs baseline: 1.2474x; 1.2474x over previous
//
#include <hip/hip_runtime.h>
#include <hip/hip_bf16.h>

#define B_    4
#define N_    20000
#define M_    20000
#define K_    16
#define CIN   64
#define CMID  16
#define COUT  67            // CIN + 3 additional channels
#define PPB   4             // one point per wave, 4 waves per block
#define NXCD  8

typedef float float4_ __attribute__((ext_vector_type(4)));
typedef short short8_ __attribute__((ext_vector_type(8)));

static __device__ __forceinline__ unsigned pk2(float lo, float hi) {
    unsigned short l = __builtin_bit_cast(unsigned short, __float2bfloat16(lo));
    unsigned short h = __builtin_bit_cast(unsigned short, __float2bfloat16(hi));
    return (unsigned)l | ((unsigned)h << 16);
}

static __device__ __forceinline__ short8_ mk8(unsigned p0, unsigned p1,
                                              unsigned p2, unsigned p3) {
    union { unsigned u[4]; short8_ s; } x;
    x.u[0] = p0; x.u[1] = p1; x.u[2] = p2; x.u[3] = p3;
    return x.s;
}

__global__ __launch_bounds__(256, 6) void pconv_kernel(
    const float* __restrict__ in_feats,   // [B, N, 64]
    const int*   __restrict__ inds,       // [B, M, 16]
    const float* __restrict__ wn,         // [B, M, 16, 16]
    const float* __restrict__ addl,       // [B, M, 16, 3]
    float*       __restrict__ out)        // [B, M, 1072]
{
    const int tid  = threadIdx.x;
    const int lane = tid & 63;
    const int wav  = tid >> 6;
    const int n16  = lane & 15;
    const int hi   = lane >> 4;

    // bijective XCD swizzle (20000 % 8 == 0)
    const int qx  = gridDim.x / NXCD;
    const int swz = (blockIdx.x % NXCD) * qx + blockIdx.x / NXCD;

    const int bp = __builtin_amdgcn_readfirstlane(swz * PPB + wav);
    const int b  = bp / M_;

    const int*   pinds = inds + (long)bp * K_;
    const float* pwn   = wn   + (long)bp * (K_ * CMID);
    const float* padd  = addl + (long)bp * (K_ * 3);
    const float* bfeat = in_feats + (long)b * N_ * CIN;

    // ---- 16 neighbor indices -> SGPRs ----
    int idxs[K_];
    #pragma unroll
    for (int k = 0; k < K_; ++k) idxs[k] = pinds[k];

    // ---- R5-optimal gathers: lane = channel c, one full 256B row per instr ----
    float f[K_];
    #pragma unroll
    for (int k = 0; k < K_; ++k)
        f[k] = bfeat[(long)idxs[k] * CIN + lane];            // 4 granules, unique

    // Slot map (R9/R11-validated): element j of lane(hi) covers kk=(hi&1)*8+j;
    // hi>=2 duplicates hi-2 in A, B zeroes those slots -> sums exactly k=0..15.
    const int kkb = (hi & 1) * 8;

    // ---- B fragment loads (fragment order, 2 granules/instr) ----
    float bwv[8];
    #pragma unroll
    for (int j = 0; j < 8; ++j)
        bwv[j] = pwn[(kkb + j) * CMID + n16];

    // ---- tail-A loads (addl channels; rows >=3 of the tile unused) ----
    const int mcl = (n16 < 3) ? n16 : 2;
    float atv[8];
    #pragma unroll
    for (int j = 0; j < 8; ++j)
        atv[j] = padd[(kkb + j) * 3 + mcl];

    // ---- pack gathered row IN SOURCE LANE: pk[q] = bf16x2(f[2q], f[2q+1]) ----
    unsigned pk[8];
    #pragma unroll
    for (int q = 0; q < 8; ++q) pk[q] = pk2(f[2 * q], f[2 * q + 1]);

    const bool realk = hi < 2;
    short8_ bfrag = mk8(realk ? pk2(bwv[0], bwv[1]) : 0u,
                        realk ? pk2(bwv[2], bwv[3]) : 0u,
                        realk ? pk2(bwv[4], bwv[5]) : 0u,
                        realk ? pk2(bwv[6], bwv[7]) : 0u);
    short8_ tfrag = mk8(pk2(atv[0], atv[1]), pk2(atv[2], atv[3]),
                        pk2(atv[4], atv[5]), pk2(atv[6], atv[7]));

    // ---- A fragments via ds_bpermute (no LDS allocation, 8 ops/tile) ----
    // dest lane (n16,hi), tile t, dword d  <-  pk[(hi&1)*4 + d] of lane t*16+n16
    const bool hiodd = (hi & 1) != 0;
    float4_ zero = (float4_)0.f;
    float4_ acc[4];
    #pragma unroll
    for (int t = 0; t < 4; ++t) {
        const int srcidx = (t * 16 + n16) * 4;               // bpermute addr = lane*4
        unsigned ad[4];
        #pragma unroll
        for (int d = 0; d < 4; ++d) {
            unsigned lo = (unsigned)__builtin_amdgcn_ds_bpermute(srcidx, (int)pk[d]);
            unsigned hv = (unsigned)__builtin_amdgcn_ds_bpermute(srcidx, (int)pk[4 + d]);
            ad[d] = hiodd ? hv : lo;
        }
        short8_ afrag = mk8(ad[0], ad[1], ad[2], ad[3]);
        acc[t] = __builtin_amdgcn_mfma_f32_16x16x32_bf16(afrag, bfrag, zero, 0, 0, 0);
    }
    float4_ acc4 = __builtin_amdgcn_mfma_f32_16x16x32_bf16(tfrag, bfrag, zero, 0, 0, 0);

    // ---- direct stores (R9-proven): D[row=hi*4+r][col=n16]; 4 full granules/instr ----
    float* pout = out + (long)bp * (COUT * CMID);
    #pragma unroll
    for (int t = 0; t < 4; ++t) {
        #pragma unroll
        for (int r = 0; r < 4; ++r)
            pout[(t * 16 + hi * 4 + r) * CMID + n16] = acc[t][r];
    }
    if (lane < 16) {                       // tail rows 0..2 = channels 64..66
        #pragma unroll
        for (int r = 0; r < 3; ++r)
            pout[(CIN + r) * CMID + n16] = acc4[r];
    }
}

extern "C" void kernel_launch(void* const* d_in, const int* in_sizes, int n_in,
                              void* d_out, int out_size, void* d_ws, size_t ws_size,
                              hipStream_t stream) {
    const float* in_feats = (const float*)d_in[0];
    const int*   ninds    = (const int*)d_in[1];
    const float* wnp      = (const float*)d_in[2];
    const float* addl     = (const float*)d_in[3];
    float*       outp     = (float*)d_out;

    const int total_points = B_ * M_;            // 80000
    dim3 grid(total_points / PPB);               // 20000 blocks, 1 point/wave
    dim3 block(256);
    pconv_kernel<<<grid, block, 0, stream>>>(in_feats, ninds, wnp, addl, outp);
}

// Round 13
// 103.840 us; speedup vs baseline: 1.6204x; 1.2990x over previous
//
#include <hip/hip_runtime.h>

#define B_    4
#define N_    20000
#define M_    20000
#define K_    16
#define CIN   64
#define CMID  16
#define COUT  67            // CIN + 3 additional channels
#define PPB   4             // one point per wave, 4 waves per block
#define LSTR  17            // padded LDS transpose stride (f32)
#define NXCD  8

typedef float float4_ __attribute__((ext_vector_type(4)));

__global__ __launch_bounds__(256, 6) void pconv_kernel(
    const float* __restrict__ in_feats,   // [B, N, 64]
    const int*   __restrict__ inds,       // [B, M, 16]
    const float* __restrict__ wn,         // [B, M, 16, 16]
    const float* __restrict__ addl,       // [B, M, 16, 3]
    float*       __restrict__ out)        // [B, M, 1072]
{
    __shared__ float lds_out[PPB][(COUT + 1) * LSTR];   // 4 x 4624 B transpose buf
    __shared__ float lds_wn [PPB][K_ * CMID];           // 4 x 1 KB

    const int tid  = threadIdx.x;
    const int lane = tid & 63;
    const int wav  = tid >> 6;

    // bijective XCD swizzle: 20000 blocks -> 2500 contiguous per XCD slot
    const int qx  = gridDim.x / NXCD;                    // 2500
    const int swz = (blockIdx.x % NXCD) * qx + blockIdx.x / NXCD;

    const int bp = __builtin_amdgcn_readfirstlane(swz * PPB + wav);
    const int b  = bp / M_;

    const int*   pinds = inds + (long)bp * K_;
    const float* pwn   = wn   + (long)bp * (K_ * CMID);
    const float* padd  = addl + (long)bp * (K_ * 3);
    const float* bfeat = in_feats + (long)b * N_ * CIN;

    // ---- wn vector load: read-once stream -> non-temporal (don't pollute L2) ----
    float4_ wstage = __builtin_nontemporal_load((const float4_*)pwn + lane);

    // ---- 16 neighbor indices -> SGPRs ----
    int idxs[K_];
    #pragma unroll
    for (int k = 0; k < K_; ++k) idxs[k] = pinds[k];

    // ---- issue ALL 16 gathers before any consumption (max MLP) ----
    float f[K_];
    #pragma unroll
    for (int k = 0; k < K_; ++k)
        f[k] = bfeat[(long)idxs[k] * CIN + lane];        // 256B coalesced each

    // stage wn to LDS (waits only on wstage's own vmcnt slot)
    *(float4_*)(&lds_wn[wav][lane * 4]) = wstage;

    // ---- FMA phase: wn via uniform ds_read_b128 broadcasts ----
    float acc[CMID];
    #pragma unroll
    for (int w = 0; w < CMID; ++w) acc[w] = 0.f;

    #pragma unroll
    for (int k = 0; k < K_; ++k) {
        const float* lw = &lds_wn[wav][k * CMID];
        float4_ w0 = *(const float4_*)(lw + 0);
        float4_ w1 = *(const float4_*)(lw + 4);
        float4_ w2 = *(const float4_*)(lw + 8);
        float4_ w3 = *(const float4_*)(lw + 12);
        #pragma unroll
        for (int e = 0; e < 4; ++e) {
            acc[0  + e] += f[k] * w0[e];
            acc[4  + e] += f[k] * w1[e];
            acc[8  + e] += f[k] * w2[e];
            acc[12 + e] += f[k] * w3[e];
        }
    }

    // ---- transpose via padded LDS (17-f32 stride: <=2-way banks, free) ----
    float* lo = &lds_out[wav][0];
    #pragma unroll
    for (int w = 0; w < CMID; ++w)
        lo[lane * LSTR + w] = acc[w];

    // tail channels c = 64+t (t=lane>>4, wt=lane&15), lanes 0..47
    const int t  = lane >> 4;
    const int wt = lane & 15;
    if (lane < 48) {
        float acc2 = 0.f;
        #pragma unroll
        for (int k = 0; k < K_; ++k) {
            float a0 = padd[k * 3 + 0];                  // uniform s_loads
            float a1 = padd[k * 3 + 1];
            float a2 = padd[k * 3 + 2];
            float av = (t == 0) ? a0 : (t == 1) ? a1 : a2;
            acc2 += av * lds_wn[wav][k * CMID + wt];     // broadcast x3, conflict-free
        }
        lo[(CIN + t) * LSTR + wt] = acc2;
    }

    // ---- readback in store-contiguous order; NT stores 4x1KB + 192B ----
    // write-once stream -> non-temporal: keep the 343MB output stream from
    // evicting the gather table out of each XCD's 4MB L2
    float* pout = out + (long)bp * (COUT * CMID);
    const int q = lane >> 2;
    const int r = lane & 3;
    #pragma unroll
    for (int p = 0; p < 4; ++p) {
        const float* src = lo + (p * 16 + q) * LSTR + 4 * r;
        float4_ v = { src[0], src[1], src[2], src[3] };
        __builtin_nontemporal_store(v, (float4_*)(pout + p * 256 + lane * 4));
    }
    if (lane < 12) {
        const float* src = lo + (CIN + q) * LSTR + 4 * r;
        float4_ v = { src[0], src[1], src[2], src[3] };
        __builtin_nontemporal_store(v, (float4_*)(pout + 1024 + lane * 4));
    }
}

extern "C" void kernel_launch(void* const* d_in, const int* in_sizes, int n_in,
                              void* d_out, int out_size, void* d_ws, size_t ws_size,
                              hipStream_t stream) {
    const float* in_feats = (const float*)d_in[0];
    const int*   ninds    = (const int*)d_in[1];
    const float* wnp      = (const float*)d_in[2];
    const float* addl     = (const float*)d_in[3];
    float*       outp     = (float*)d_out;

    const int total_points = B_ * M_;            // 80000
    dim3 grid(total_points / PPB);               // 20000 blocks, 1 point/wave
    dim3 block(256);
    pconv_kernel<<<grid, block, 0, stream>>>(in_feats, ninds, wnp, addl, outp);
}